// Round 2
// baseline (6837.367 us; speedup 1.0000x reference)
//
#include <hip/hip_runtime.h>
#include <hip/hip_bf16.h>
#include <stdint.h>

// Problem constants
#define NN 20000      // nodes
#define NE 640000     // edges
#define HID 512
#define MID 4352
#define VOC 8192

typedef __attribute__((ext_vector_type(4))) float f32x4;
typedef __attribute__((ext_vector_type(8))) short bf16x8;

__device__ __forceinline__ unsigned short f2bf(float f) {
  unsigned int u = __float_as_uint(f);
  u += 0x7fffu + ((u >> 16) & 1u);   // round-to-nearest-even
  return (unsigned short)(u >> 16);
}

// ---------------- detect edge_index storage width ----------------
// If edge_index is delivered as int64, every odd int32 position is a high
// word == 0 (indices < 2^31). If int32, odd positions are random node ids.
__global__ void k_detect64(const int* __restrict__ ei32, int* __restrict__ flag) {
  __shared__ int any_nz;
  if (threadIdx.x == 0) any_nz = 0;
  __syncthreads();
  int v = ei32[2 * threadIdx.x + 1];   // int32 positions 1,3,...,511 (2 KB, safe)
  if (v != 0) atomicOr(&any_nz, 1);
  __syncthreads();
  if (threadIdx.x == 0) *flag = (any_nz == 0) ? 1 : 0;  // 1 => int64 layout
}

// ---------------- h = x (f32 copy, vectorized) ----------------
__global__ void k_copy_f32(const float4* __restrict__ src, float4* __restrict__ dst, int n4) {
  int i = blockIdx.x * blockDim.x + threadIdx.x;
  int stride = gridDim.x * blockDim.x;
  for (; i < n4; i += stride) dst[i] = src[i];
}

// ---------------- scatter: h[dst] += x[src] ----------------
// one thread per (edge, 4-col chunk): 640000 * 128 items
__global__ void k_scatter(const float4* __restrict__ x4, const int* __restrict__ ei,
                          const int* __restrict__ flag, float* __restrict__ h) {
  long long i = (long long)blockIdx.x * blockDim.x + threadIdx.x;
  const long long total = (long long)NE * 128;
  if (i >= total) return;
  int e  = (int)(i >> 7);
  int c4 = (int)(i & 127);
  int is64 = *flag;   // uniform, L2-cached
  int s, d;
  if (is64) { s = ei[2 * e];      d = ei[2 * (NE + e)]; }
  else      { s = ei[e];          d = ei[NE + e]; }
  if ((unsigned)s >= NN || (unsigned)d >= NN) return;  // safety: never OOB
  float4 v = x4[(long long)s * 128 + c4];
  float* hp = h + (long long)d * 512 + (long long)c4 * 4;
  atomicAdd(hp + 0, v.x);
  atomicAdd(hp + 1, v.y);
  atomicAdd(hp + 2, v.z);
  atomicAdd(hp + 3, v.w);
}

// ---------------- f32 -> bf16 (4 elems/thread) ----------------
__global__ void k_f32_to_bf16(const float4* __restrict__ src, uint2* __restrict__ dst, int n4) {
  int i = blockIdx.x * blockDim.x + threadIdx.x;
  int stride = gridDim.x * blockDim.x;
  for (; i < n4; i += stride) {
    float4 v = src[i];
    uint2 o;
    o.x = (unsigned)f2bf(v.x) | ((unsigned)f2bf(v.y) << 16);
    o.y = (unsigned)f2bf(v.z) | ((unsigned)f2bf(v.w) << 16);
    dst[i] = o;
  }
}

// ---------------- bf16 GEMM: C[M,N] = A[M,K] * B[N,K]^T + bias ----------------
// m97-style: 128x128 tile, BK=32, 256 threads = 4 waves (2x2), each wave 64x64
// via 4x4 grid of 16x16x32 MFMA. global_load_lds width-16 staging.
template<bool OUT_BF16>
__global__ __launch_bounds__(256)
void k_gemm_bt(const unsigned short* __restrict__ A,   // [M,K] bf16
               const unsigned short* __restrict__ B,   // [N,K] bf16
               const float* __restrict__ bias,         // [N]
               void* __restrict__ C,                   // [M,N] f32 or bf16
               int M, int N, int K)
{
  __shared__ __align__(16) unsigned short ldsA[128 * 32];
  __shared__ __align__(16) unsigned short ldsB[128 * 32];

  const int tid  = threadIdx.x;
  const int lane = tid & 63;
  const int w    = tid >> 6;       // wave 0..3
  const int wr   = w >> 1;         // wave row (0..1)
  const int wc   = w & 1;          // wave col (0..1)
  const int bm   = blockIdx.y;
  const int bn   = blockIdx.x;

  const int l4r = lane >> 2;            // 0..15  (row within 16-row chunk)
  const int l4c = (lane & 3) * 8;       // 0,8,16,24 (k-col, 8 bf16 = 16B)

  f32x4 acc[4][4] = {};

  const int kTiles = K >> 5;            // K/32
  for (int kt = 0; kt < kTiles; ++kt) {
    const int k0 = (kt << 5) + l4c;
    // stage A,B tiles: each wave fills two 1KB chunks of each
#pragma unroll
    for (int c = 0; c < 2; ++c) {
      const int ch  = w * 2 + c;            // 0..7
      const int row = ch * 16 + l4r;        // 0..127
      const int ga  = min(bm * 128 + row, M - 1);   // clamp M-edge
      const int gb  = bn * 128 + row;               // N always divisible by 128
      __builtin_amdgcn_global_load_lds(
          (const __attribute__((address_space(1))) void*)(A + (long long)ga * K + k0),
          (__attribute__((address_space(3))) void*)(&ldsA[ch * 512]), 16, 0, 0);
      __builtin_amdgcn_global_load_lds(
          (const __attribute__((address_space(1))) void*)(B + (long long)gb * K + k0),
          (__attribute__((address_space(3))) void*)(&ldsB[ch * 512]), 16, 0, 0);
    }
    asm volatile("s_waitcnt vmcnt(0)");
    __syncthreads();

    bf16x8 af[4], bfr[4];
#pragma unroll
    for (int m = 0; m < 4; ++m)
      af[m] = *(const bf16x8*)&ldsA[(wr * 64 + m * 16 + (lane & 15)) * 32 + (lane >> 4) * 8];
#pragma unroll
    for (int n = 0; n < 4; ++n)
      bfr[n] = *(const bf16x8*)&ldsB[(wc * 64 + n * 16 + (lane & 15)) * 32 + (lane >> 4) * 8];

#pragma unroll
    for (int m = 0; m < 4; ++m)
#pragma unroll
      for (int n = 0; n < 4; ++n)
        acc[m][n] = __builtin_amdgcn_mfma_f32_16x16x32_bf16(af[m], bfr[n], acc[m][n], 0, 0, 0);

    __syncthreads();
  }

  // epilogue: C row = (lane>>4)*4 + j, col = lane&15 within each 16x16 frag
#pragma unroll
  for (int n = 0; n < 4; ++n) {
    const int col = bn * 128 + wc * 64 + n * 16 + (lane & 15);
    const float bv = bias[col];
#pragma unroll
    for (int m = 0; m < 4; ++m) {
      const int row0 = bm * 128 + wr * 64 + m * 16 + ((lane >> 4) << 2);
#pragma unroll
      for (int j = 0; j < 4; ++j) {
        const int row = row0 + j;
        if (row < M) {
          const float v = acc[m][n][j] + bv;
          if (OUT_BF16)
            ((unsigned short*)C)[(long long)row * N + col] = f2bf(v);
          else
            ((float*)C)[(long long)row * N + col] = v;
        }
      }
    }
  }
}

extern "C" void kernel_launch(void* const* d_in, const int* in_sizes, int n_in,
                              void* d_out, int out_size, void* d_ws, size_t ws_size,
                              hipStream_t stream) {
  const float* x  = (const float*)d_in[0];
  const int*   ei = (const int*)d_in[1];      // int32 or int64 — detected on device
  const float* W1 = (const float*)d_in[2];
  const float* b1 = (const float*)d_in[3];
  const float* W2 = (const float*)d_in[4];
  const float* b2 = (const float*)d_in[5];
  float* out = (float*)d_out;
  char* ws = (char*)d_ws;

  // workspace layout (bytes), 256B-aligned blocks
  int*            flag = (int*)(ws + 0);                        // 4 B (+pad)
  float*          h    = (float*)(ws + 256);                    // 40,960,000
  unsigned short* hb   = (unsigned short*)(ws + 256 + 40960000);          // 20,480,000
  unsigned short* w1b  = (unsigned short*)(ws + 256 + 61440000);          //  4,456,448
  unsigned short* w2b  = (unsigned short*)(ws + 256 + 65896448);          // 71,303,168
  const size_t h1_off  = 256 + 137199616;
  if (ws_size < h1_off + (size_t)128 * MID * 2) return;  // cannot run safely
  unsigned short* h1b  = (unsigned short*)(ws + h1_off);

  // h1 chunk rows: as many 128-row blocks as fit in remaining workspace
  long long rem = (long long)ws_size - (long long)h1_off;
  int max_rows = (int)(rem / ((long long)MID * 2));
  max_rows = (max_rows / 128) * 128;
  if (max_rows > 20096) max_rows = 20096;

  // 0) detect edge_index width
  k_detect64<<<1, 256, 0, stream>>>(ei, flag);

  // 1) h = x
  k_copy_f32<<<2048, 256, 0, stream>>>((const float4*)x, (float4*)h, NN * HID / 4);

  // 2) scatter-add over edges
  {
    long long total = (long long)NE * 128;
    int blocks = (int)((total + 255) / 256);
    k_scatter<<<blocks, 256, 0, stream>>>((const float4*)x, ei, flag, h);
  }

  // 3) conversions to bf16
  k_f32_to_bf16<<<2048, 256, 0, stream>>>((const float4*)h,  (uint2*)hb,  NN * HID / 4);
  k_f32_to_bf16<<<1024, 256, 0, stream>>>((const float4*)W1, (uint2*)w1b, MID * HID / 4);
  k_f32_to_bf16<<<2048, 256, 0, stream>>>((const float4*)W2, (uint2*)w2b, VOC * MID / 4);

  // 4+5) chunked GEMM1 -> GEMM2 over M
  for (int r0 = 0; r0 < NN; r0 += max_rows) {
    int mrows = (NN - r0 < max_rows) ? (NN - r0) : max_rows;
    dim3 g1(MID / 128, (mrows + 127) / 128);
    k_gemm_bt<true><<<g1, 256, 0, stream>>>(hb + (size_t)r0 * HID, w1b, b1,
                                            (void*)h1b, mrows, MID, HID);
    dim3 g2(VOC / 128, (mrows + 127) / 128);
    k_gemm_bt<false><<<g2, 256, 0, stream>>>(h1b, w2b, b2,
                                             (void*)(out + (size_t)r0 * VOC), mrows, VOC, MID);
  }
}

// Round 3
// 2750.558 us; speedup vs baseline: 2.4858x; 2.4858x over previous
//
#include <hip/hip_runtime.h>
#include <hip/hip_bf16.h>
#include <stdint.h>

// Problem constants
#define NN 20000      // nodes
#define NE 640000     // edges
#define HID 512
#define MID 4352
#define VOC 8192

typedef __attribute__((ext_vector_type(4))) float f32x4;
typedef __attribute__((ext_vector_type(8))) short bf16x8;

__device__ __forceinline__ unsigned short f2bf(float f) {
  unsigned int u = __float_as_uint(f);
  u += 0x7fffu + ((u >> 16) & 1u);   // round-to-nearest-even
  return (unsigned short)(u >> 16);
}

// ---------------- detect edge_index storage width ----------------
// If edge_index is delivered as int64, every odd int32 position is a high
// word == 0 (indices < 2^31). If int32, odd positions are random node ids.
__global__ void k_detect64(const int* __restrict__ ei32, int* __restrict__ flag) {
  __shared__ int any_nz;
  if (threadIdx.x == 0) any_nz = 0;
  __syncthreads();
  int v = ei32[2 * threadIdx.x + 1];
  if (v != 0) atomicOr(&any_nz, 1);
  __syncthreads();
  if (threadIdx.x == 0) *flag = (any_nz == 0) ? 1 : 0;  // 1 => int64 layout
}

// ---------------- zero int buffer ----------------
__global__ void k_zero_i32(int* __restrict__ p, int n) {
  int i = blockIdx.x * blockDim.x + threadIdx.x;
  if (i < n) p[i] = 0;
}

// ---------------- degree histogram over dst ----------------
__global__ void k_count(const int* __restrict__ ei, const int* __restrict__ flag,
                        int* __restrict__ deg) {
  int e = blockIdx.x * blockDim.x + threadIdx.x;
  if (e >= NE) return;
  int is64 = *flag;
  int d = is64 ? ei[2 * (NE + e)] : ei[NE + e];
  if ((unsigned)d >= NN) return;
  atomicAdd(&deg[d], 1);
}

// ---------------- single-block exclusive scan (20000 elems) ----------------
__global__ __launch_bounds__(1024)
void k_scan(const int* __restrict__ deg, int* __restrict__ offs, int* __restrict__ cursor) {
  __shared__ int part[1024];
  const int t = threadIdx.x;
  const int CH = (NN + 1023) / 1024;  // 20
  const int base = t * CH;
  int s = 0;
  for (int i = 0; i < CH; ++i) { int idx = base + i; if (idx < NN) s += deg[idx]; }
  part[t] = s;
  __syncthreads();
  for (int off = 1; off < 1024; off <<= 1) {
    int v = (t >= off) ? part[t - off] : 0;
    __syncthreads();
    part[t] += v;
    __syncthreads();
  }
  int run = (t == 0) ? 0 : part[t - 1];  // exclusive prefix
  for (int i = 0; i < CH; ++i) {
    int idx = base + i;
    if (idx < NN) { offs[idx] = run; cursor[idx] = run; run += deg[idx]; }
  }
}

// ---------------- fill CSR: csr[pos] = src ----------------
__global__ void k_fill(const int* __restrict__ ei, const int* __restrict__ flag,
                       int* __restrict__ cursor, int* __restrict__ csr) {
  int e = blockIdx.x * blockDim.x + threadIdx.x;
  if (e >= NE) return;
  int is64 = *flag;
  int s, d;
  if (is64) { s = ei[2 * e]; d = ei[2 * (NE + e)]; }
  else      { s = ei[e];     d = ei[NE + e]; }
  if ((unsigned)s >= NN || (unsigned)d >= NN) return;
  int pos = atomicAdd(&cursor[d], 1);
  csr[pos] = s;
}

// ---------------- fused gather + (1+eps)*x + bf16 convert ----------------
// one wave per node; lane handles 8 cols (two float4); writes bf16 row chunk
__global__ __launch_bounds__(256)
void k_gather_bf16(const float4* __restrict__ x4, const int* __restrict__ offs,
                   const int* __restrict__ deg, const int* __restrict__ csr,
                   uint4* __restrict__ hb4) {
  const int wid = blockIdx.x * (blockDim.x >> 6) + (threadIdx.x >> 6);
  if (wid >= NN) return;
  const int lane = threadIdx.x & 63;
  const long long rb0 = (long long)wid * 128 + lane * 2;
  float4 a0 = x4[rb0];
  float4 a1 = x4[rb0 + 1];
  const int beg = offs[wid];
  const int dc  = deg[wid];
  for (int j = 0; j < dc; ++j) {
    int s = csr[beg + j];
    long long rb = (long long)s * 128 + lane * 2;
    float4 v0 = x4[rb];
    float4 v1 = x4[rb + 1];
    a0.x += v0.x; a0.y += v0.y; a0.z += v0.z; a0.w += v0.w;
    a1.x += v1.x; a1.y += v1.y; a1.z += v1.z; a1.w += v1.w;
  }
  uint4 o;
  o.x = (unsigned)f2bf(a0.x) | ((unsigned)f2bf(a0.y) << 16);
  o.y = (unsigned)f2bf(a0.z) | ((unsigned)f2bf(a0.w) << 16);
  o.z = (unsigned)f2bf(a1.x) | ((unsigned)f2bf(a1.y) << 16);
  o.w = (unsigned)f2bf(a1.z) | ((unsigned)f2bf(a1.w) << 16);
  hb4[(long long)wid * 64 + lane] = o;
}

// ---------------- f32 -> bf16 (4 elems/thread) ----------------
__global__ void k_f32_to_bf16(const float4* __restrict__ src, uint2* __restrict__ dst, int n4) {
  int i = blockIdx.x * blockDim.x + threadIdx.x;
  int stride = gridDim.x * blockDim.x;
  for (; i < n4; i += stride) {
    float4 v = src[i];
    uint2 o;
    o.x = (unsigned)f2bf(v.x) | ((unsigned)f2bf(v.y) << 16);
    o.y = (unsigned)f2bf(v.z) | ((unsigned)f2bf(v.w) << 16);
    dst[i] = o;
  }
}

// ---------------- bf16 GEMM: C[M,N] = A[M,K] * B[N,K]^T + bias ----------------
// m97-style: 128x128 tile, BK=32, 4 waves (2x2), 16x16x32 MFMA,
// global_load_lds width-16 staging, T1 bijective XCD swizzle.
template<bool OUT_BF16>
__global__ __launch_bounds__(256)
void k_gemm_bt(const unsigned short* __restrict__ A,   // [M,K] bf16
               const unsigned short* __restrict__ B,   // [N,K] bf16
               const float* __restrict__ bias,         // [N]
               void* __restrict__ C,                   // [M,N] f32 or bf16
               int M, int N, int K)
{
  __shared__ __align__(16) unsigned short ldsA[128 * 32];
  __shared__ __align__(16) unsigned short ldsB[128 * 32];

  const int tid  = threadIdx.x;
  const int lane = tid & 63;
  const int w    = tid >> 6;
  const int wr   = w >> 1;
  const int wc   = w & 1;

  // T1: bijective XCD swizzle (m204)
  const int nwg  = gridDim.x * gridDim.y;
  const int orig = blockIdx.y * gridDim.x + blockIdx.x;
  const int q = nwg >> 3, r = nwg & 7;
  const int xcd = orig & 7, land = orig >> 3;
  const int nid = (xcd < r ? xcd * (q + 1) : r * (q + 1) + (xcd - r) * q) + land;
  const int bn = nid % gridDim.x;
  const int bm = nid / gridDim.x;

  const int l4r = lane >> 2;
  const int l4c = (lane & 3) * 8;

  f32x4 acc[4][4] = {};

  const int kTiles = K >> 5;
  for (int kt = 0; kt < kTiles; ++kt) {
    const int k0 = (kt << 5) + l4c;
#pragma unroll
    for (int c = 0; c < 2; ++c) {
      const int ch  = w * 2 + c;
      const int row = ch * 16 + l4r;
      const int ga  = min(bm * 128 + row, M - 1);
      const int gb  = bn * 128 + row;
      __builtin_amdgcn_global_load_lds(
          (const __attribute__((address_space(1))) void*)(A + (long long)ga * K + k0),
          (__attribute__((address_space(3))) void*)(&ldsA[ch * 512]), 16, 0, 0);
      __builtin_amdgcn_global_load_lds(
          (const __attribute__((address_space(1))) void*)(B + (long long)gb * K + k0),
          (__attribute__((address_space(3))) void*)(&ldsB[ch * 512]), 16, 0, 0);
    }
    asm volatile("s_waitcnt vmcnt(0)");
    __syncthreads();

    bf16x8 af[4], bfr[4];
#pragma unroll
    for (int m = 0; m < 4; ++m)
      af[m] = *(const bf16x8*)&ldsA[(wr * 64 + m * 16 + (lane & 15)) * 32 + (lane >> 4) * 8];
#pragma unroll
    for (int n = 0; n < 4; ++n)
      bfr[n] = *(const bf16x8*)&ldsB[(wc * 64 + n * 16 + (lane & 15)) * 32 + (lane >> 4) * 8];

#pragma unroll
    for (int m = 0; m < 4; ++m)
#pragma unroll
      for (int n = 0; n < 4; ++n)
        acc[m][n] = __builtin_amdgcn_mfma_f32_16x16x32_bf16(af[m], bfr[n], acc[m][n], 0, 0, 0);

    __syncthreads();
  }

#pragma unroll
  for (int n = 0; n < 4; ++n) {
    const int col = bn * 128 + wc * 64 + n * 16 + (lane & 15);
    const float bv = bias[col];
#pragma unroll
    for (int m = 0; m < 4; ++m) {
      const int row0 = bm * 128 + wr * 64 + m * 16 + ((lane >> 4) << 2);
#pragma unroll
      for (int j = 0; j < 4; ++j) {
        const int row = row0 + j;
        if (row < M) {
          const float v = acc[m][n][j] + bv;
          if (OUT_BF16)
            ((unsigned short*)C)[(long long)row * N + col] = f2bf(v);
          else
            ((float*)C)[(long long)row * N + col] = v;
        }
      }
    }
  }
}

extern "C" void kernel_launch(void* const* d_in, const int* in_sizes, int n_in,
                              void* d_out, int out_size, void* d_ws, size_t ws_size,
                              hipStream_t stream) {
  const float* x  = (const float*)d_in[0];
  const int*   ei = (const int*)d_in[1];      // int32 or int64 — detected on device
  const float* W1 = (const float*)d_in[2];
  const float* b1 = (const float*)d_in[3];
  const float* W2 = (const float*)d_in[4];
  const float* b2 = (const float*)d_in[5];
  float* out = (float*)d_out;
  char* ws = (char*)d_ws;

  // workspace layout (bytes, 16B-aligned)
  int* flag            = (int*)(ws + 0);                 // 256
  int* deg             = (int*)(ws + 256);               // 80,000
  int* offs            = (int*)(ws + 80256);             // 80,000
  int* cursor          = (int*)(ws + 160256);            // 80,000
  int* csr             = (int*)(ws + 240256);            // 2,560,000
  unsigned short* hb   = (unsigned short*)(ws + 2800256);   // 20,480,000
  unsigned short* w1b  = (unsigned short*)(ws + 23280256);  //  4,456,448
  unsigned short* w2b  = (unsigned short*)(ws + 27736704);  // 71,303,168
  const size_t h1_off  = 99039872;
  if (ws_size < h1_off + (size_t)128 * MID * 2) return;
  unsigned short* h1b  = (unsigned short*)(ws + h1_off);

  long long rem = (long long)ws_size - (long long)h1_off;
  int max_rows = (int)(rem / ((long long)MID * 2));
  max_rows = (max_rows / 128) * 128;
  if (max_rows > 20096) max_rows = 20096;

  // 0) detect edge_index width
  k_detect64<<<1, 256, 0, stream>>>(ei, flag);

  // 1) CSR build
  k_zero_i32<<<(NN + 255) / 256, 256, 0, stream>>>(deg, NN);
  k_count<<<(NE + 255) / 256, 256, 0, stream>>>(ei, flag, deg);
  k_scan<<<1, 1024, 0, stream>>>(deg, offs, cursor);
  k_fill<<<(NE + 255) / 256, 256, 0, stream>>>(ei, flag, cursor, csr);

  // 2) fused gather + bf16 convert: hb = bf16(x + sum_{j->i} x_j)
  k_gather_bf16<<<(NN + 3) / 4, 256, 0, stream>>>((const float4*)x, offs, deg, csr,
                                                  (uint4*)hb);

  // 3) weight conversions to bf16
  k_f32_to_bf16<<<1024, 256, 0, stream>>>((const float4*)W1, (uint2*)w1b, MID * HID / 4);
  k_f32_to_bf16<<<2048, 256, 0, stream>>>((const float4*)W2, (uint2*)w2b, VOC * MID / 4);

  // 4+5) chunked GEMM1 -> GEMM2 over M
  for (int r0 = 0; r0 < NN; r0 += max_rows) {
    int mrows = (NN - r0 < max_rows) ? (NN - r0) : max_rows;
    dim3 g1(MID / 128, (mrows + 127) / 128);
    k_gemm_bt<true><<<g1, 256, 0, stream>>>(hb + (size_t)r0 * HID, w1b, b1,
                                            (void*)h1b, mrows, MID, HID);
    dim3 g2(VOC / 128, (mrows + 127) / 128);
    k_gemm_bt<false><<<g2, 256, 0, stream>>>(h1b, w2b, b2,
                                             (void*)(out + (size_t)r0 * VOC), mrows, VOC, MID);
  }
}

// Round 4
// 2512.295 us; speedup vs baseline: 2.7216x; 1.0948x over previous
//
#include <hip/hip_runtime.h>
#include <hip/hip_bf16.h>
#include <stdint.h>

// Problem constants
#define NN 20000      // nodes
#define NE 640000     // edges
#define HID 512
#define MID 4352
#define VOC 8192

typedef __attribute__((ext_vector_type(4))) float f32x4;
typedef __attribute__((ext_vector_type(8))) short bf16x8;

__device__ __forceinline__ unsigned short f2bf(float f) {
  unsigned int u = __float_as_uint(f);
  u += 0x7fffu + ((u >> 16) & 1u);   // round-to-nearest-even
  return (unsigned short)(u >> 16);
}

// ---------------- detect edge_index storage width ----------------
__global__ void k_detect64(const int* __restrict__ ei32, int* __restrict__ flag) {
  __shared__ int any_nz;
  if (threadIdx.x == 0) any_nz = 0;
  __syncthreads();
  int v = ei32[2 * threadIdx.x + 1];
  if (v != 0) atomicOr(&any_nz, 1);
  __syncthreads();
  if (threadIdx.x == 0) *flag = (any_nz == 0) ? 1 : 0;  // 1 => int64 layout
}

// ---------------- zero int buffer ----------------
__global__ void k_zero_i32(int* __restrict__ p, int n) {
  int i = blockIdx.x * blockDim.x + threadIdx.x;
  if (i < n) p[i] = 0;
}

// ---------------- degree histogram over dst ----------------
__global__ void k_count(const int* __restrict__ ei, const int* __restrict__ flag,
                        int* __restrict__ deg) {
  int e = blockIdx.x * blockDim.x + threadIdx.x;
  if (e >= NE) return;
  int is64 = *flag;
  int d = is64 ? ei[2 * (NE + e)] : ei[NE + e];
  if ((unsigned)d >= NN) return;
  atomicAdd(&deg[d], 1);
}

// ---------------- single-block exclusive scan (20000 elems) ----------------
__global__ __launch_bounds__(1024)
void k_scan(const int* __restrict__ deg, int* __restrict__ offs, int* __restrict__ cursor) {
  __shared__ int part[1024];
  const int t = threadIdx.x;
  const int CH = (NN + 1023) / 1024;  // 20
  const int base = t * CH;
  int s = 0;
  for (int i = 0; i < CH; ++i) { int idx = base + i; if (idx < NN) s += deg[idx]; }
  part[t] = s;
  __syncthreads();
  for (int off = 1; off < 1024; off <<= 1) {
    int v = (t >= off) ? part[t - off] : 0;
    __syncthreads();
    part[t] += v;
    __syncthreads();
  }
  int run = (t == 0) ? 0 : part[t - 1];  // exclusive prefix
  for (int i = 0; i < CH; ++i) {
    int idx = base + i;
    if (idx < NN) { offs[idx] = run; cursor[idx] = run; run += deg[idx]; }
  }
}

// ---------------- fill CSR: csr[pos] = src ----------------
__global__ void k_fill(const int* __restrict__ ei, const int* __restrict__ flag,
                       int* __restrict__ cursor, int* __restrict__ csr) {
  int e = blockIdx.x * blockDim.x + threadIdx.x;
  if (e >= NE) return;
  int is64 = *flag;
  int s, d;
  if (is64) { s = ei[2 * e]; d = ei[2 * (NE + e)]; }
  else      { s = ei[e];     d = ei[NE + e]; }
  if ((unsigned)s >= NN || (unsigned)d >= NN) return;
  int pos = atomicAdd(&cursor[d], 1);
  csr[pos] = s;
}

// ---------------- fused gather + (1+eps)*x + bf16 convert ----------------
__global__ __launch_bounds__(256)
void k_gather_bf16(const float4* __restrict__ x4, const int* __restrict__ offs,
                   const int* __restrict__ deg, const int* __restrict__ csr,
                   uint4* __restrict__ hb4) {
  const int wid = blockIdx.x * (blockDim.x >> 6) + (threadIdx.x >> 6);
  if (wid >= NN) return;
  const int lane = threadIdx.x & 63;
  const long long rb0 = (long long)wid * 128 + lane * 2;
  float4 a0 = x4[rb0];
  float4 a1 = x4[rb0 + 1];
  const int beg = offs[wid];
  const int dc  = deg[wid];
  for (int j = 0; j < dc; ++j) {
    int s = csr[beg + j];
    long long rb = (long long)s * 128 + lane * 2;
    float4 v0 = x4[rb];
    float4 v1 = x4[rb + 1];
    a0.x += v0.x; a0.y += v0.y; a0.z += v0.z; a0.w += v0.w;
    a1.x += v1.x; a1.y += v1.y; a1.z += v1.z; a1.w += v1.w;
  }
  uint4 o;
  o.x = (unsigned)f2bf(a0.x) | ((unsigned)f2bf(a0.y) << 16);
  o.y = (unsigned)f2bf(a0.z) | ((unsigned)f2bf(a0.w) << 16);
  o.z = (unsigned)f2bf(a1.x) | ((unsigned)f2bf(a1.y) << 16);
  o.w = (unsigned)f2bf(a1.z) | ((unsigned)f2bf(a1.w) << 16);
  hb4[(long long)wid * 64 + lane] = o;
}

// ---------------- f32 -> bf16 (4 elems/thread) ----------------
__global__ void k_f32_to_bf16(const float4* __restrict__ src, uint2* __restrict__ dst, int n4) {
  int i = blockIdx.x * blockDim.x + threadIdx.x;
  int stride = gridDim.x * blockDim.x;
  for (; i < n4; i += stride) {
    float4 v = src[i];
    uint2 o;
    o.x = (unsigned)f2bf(v.x) | ((unsigned)f2bf(v.y) << 16);
    o.y = (unsigned)f2bf(v.z) | ((unsigned)f2bf(v.w) << 16);
    dst[i] = o;
  }
}

// ---------------- bf16 GEMM: C[M,N] = A[M,K] * B[N,K]^T + bias ----------------
// 128x128 tile, BK=32, 4 waves (2x2), 16x16x32 MFMA, global_load_lds staging.
// LDS seg-swizzle: phys_seg = seg ^ ((row>>1)&3), applied BOTH sides
// (pre-swizzled global source + swizzled ds_read) per rule #21.
// Grid: bn-chunk-per-XCD mapping when gx%8==0, else m204 bijective swizzle.
// f32 output uses non-temporal stores (don't evict A/B panels from L2/L3).
template<bool OUT_BF16>
__global__ __launch_bounds__(256)
void k_gemm_bt(const unsigned short* __restrict__ A,   // [M,K] bf16
               const unsigned short* __restrict__ B,   // [N,K] bf16
               const float* __restrict__ bias,         // [N]
               void* __restrict__ C,                   // [M,N] f32 or bf16
               int M, int N, int K)
{
  __shared__ __align__(16) unsigned short ldsA[128 * 32];
  __shared__ __align__(16) unsigned short ldsB[128 * 32];

  const int tid  = threadIdx.x;
  const int lane = tid & 63;
  const int w    = tid >> 6;
  const int wr   = w >> 1;
  const int wc   = w & 1;

  // grid mapping
  const int nwg  = gridDim.x * gridDim.y;
  const int orig = blockIdx.y * gridDim.x + blockIdx.x;
  int bn, bm;
  if ((gridDim.x & 7) == 0 && (nwg & 7) == 0) {
    // bn-chunk per XCD: each XCD owns gx/8 consecutive bn panels, sweeps bm
    const int xcd = orig & 7;
    const int j   = orig >> 3;
    const int chunk = gridDim.x >> 3;
    bn = xcd * chunk + (j % chunk);
    bm = j / chunk;
  } else {
    // m204 bijective XCD swizzle
    const int q = nwg >> 3, r = nwg & 7;
    const int xcd = orig & 7, land = orig >> 3;
    const int nid = (xcd < r ? xcd * (q + 1) : r * (q + 1) + (xcd - r) * q) + land;
    bn = nid % gridDim.x;
    bm = nid / gridDim.x;
  }

  const int l4r  = lane >> 2;                          // row in 16-row chunk
  const int sseg = (lane & 3) ^ ((lane >> 3) & 3);     // pre-swizzled source seg
  const int l4c  = sseg * 8;                           // source k-col (elems)

  f32x4 acc[4][4] = {};

  const int kTiles = K >> 5;
  for (int kt = 0; kt < kTiles; ++kt) {
    const int k0 = (kt << 5) + l4c;
#pragma unroll
    for (int c = 0; c < 2; ++c) {
      const int ch  = w * 2 + c;
      const int row = ch * 16 + l4r;
      const int ga  = min(bm * 128 + row, M - 1);
      const int gb  = bn * 128 + row;
      __builtin_amdgcn_global_load_lds(
          (const __attribute__((address_space(1))) void*)(A + (long long)ga * K + k0),
          (__attribute__((address_space(3))) void*)(&ldsA[ch * 512]), 16, 0, 0);
      __builtin_amdgcn_global_load_lds(
          (const __attribute__((address_space(1))) void*)(B + (long long)gb * K + k0),
          (__attribute__((address_space(3))) void*)(&ldsB[ch * 512]), 16, 0, 0);
    }
    asm volatile("s_waitcnt vmcnt(0)");
    __syncthreads();

    bf16x8 af[4], bfr[4];
#pragma unroll
    for (int m = 0; m < 4; ++m) {
      const int RA = wr * 64 + m * 16 + (lane & 15);
      const int sp = (lane >> 4) ^ ((RA >> 1) & 3);    // swizzled read seg
      af[m] = *(const bf16x8*)&ldsA[RA * 32 + sp * 8];
    }
#pragma unroll
    for (int n = 0; n < 4; ++n) {
      const int RB = wc * 64 + n * 16 + (lane & 15);
      const int sp = (lane >> 4) ^ ((RB >> 1) & 3);
      bfr[n] = *(const bf16x8*)&ldsB[RB * 32 + sp * 8];
    }

#pragma unroll
    for (int m = 0; m < 4; ++m)
#pragma unroll
      for (int n = 0; n < 4; ++n)
        acc[m][n] = __builtin_amdgcn_mfma_f32_16x16x32_bf16(af[m], bfr[n], acc[m][n], 0, 0, 0);

    __syncthreads();
  }

#pragma unroll
  for (int n = 0; n < 4; ++n) {
    const int col = bn * 128 + wc * 64 + n * 16 + (lane & 15);
    const float bv = bias[col];
#pragma unroll
    for (int m = 0; m < 4; ++m) {
      const int row0 = bm * 128 + wr * 64 + m * 16 + ((lane >> 4) << 2);
#pragma unroll
      for (int j = 0; j < 4; ++j) {
        const int row = row0 + j;
        if (row < M) {
          const float v = acc[m][n][j] + bv;
          if (OUT_BF16)
            ((unsigned short*)C)[(long long)row * N + col] = f2bf(v);
          else
            __builtin_nontemporal_store(v, &((float*)C)[(long long)row * N + col]);
        }
      }
    }
  }
}

extern "C" void kernel_launch(void* const* d_in, const int* in_sizes, int n_in,
                              void* d_out, int out_size, void* d_ws, size_t ws_size,
                              hipStream_t stream) {
  const float* x  = (const float*)d_in[0];
  const int*   ei = (const int*)d_in[1];      // int32 or int64 — detected on device
  const float* W1 = (const float*)d_in[2];
  const float* b1 = (const float*)d_in[3];
  const float* W2 = (const float*)d_in[4];
  const float* b2 = (const float*)d_in[5];
  float* out = (float*)d_out;
  char* ws = (char*)d_ws;

  // workspace layout (bytes, 16B-aligned)
  int* flag            = (int*)(ws + 0);                 // 256
  int* deg             = (int*)(ws + 256);               // 80,000
  int* offs            = (int*)(ws + 80256);             // 80,000
  int* cursor          = (int*)(ws + 160256);            // 80,000
  int* csr             = (int*)(ws + 240256);            // 2,560,000
  unsigned short* hb   = (unsigned short*)(ws + 2800256);   // 20,480,000
  unsigned short* w1b  = (unsigned short*)(ws + 23280256);  //  4,456,448
  unsigned short* w2b  = (unsigned short*)(ws + 27736704);  // 71,303,168
  const size_t h1_off  = 99039872;
  if (ws_size < h1_off + (size_t)128 * MID * 2) return;
  unsigned short* h1b  = (unsigned short*)(ws + h1_off);

  long long rem = (long long)ws_size - (long long)h1_off;
  int max_rows = (int)(rem / ((long long)MID * 2));
  max_rows = (max_rows / 128) * 128;
  if (max_rows > 20096) max_rows = 20096;

  // 0) detect edge_index width
  k_detect64<<<1, 256, 0, stream>>>(ei, flag);

  // 1) CSR build
  k_zero_i32<<<(NN + 255) / 256, 256, 0, stream>>>(deg, NN);
  k_count<<<(NE + 255) / 256, 256, 0, stream>>>(ei, flag, deg);
  k_scan<<<1, 1024, 0, stream>>>(deg, offs, cursor);
  k_fill<<<(NE + 255) / 256, 256, 0, stream>>>(ei, flag, cursor, csr);

  // 2) fused gather + bf16 convert: hb = bf16(x + sum_{j->i} x_j)
  k_gather_bf16<<<(NN + 3) / 4, 256, 0, stream>>>((const float4*)x, offs, deg, csr,
                                                  (uint4*)hb);

  // 3) weight conversions to bf16
  k_f32_to_bf16<<<1024, 256, 0, stream>>>((const float4*)W1, (uint2*)w1b, MID * HID / 4);
  k_f32_to_bf16<<<2048, 256, 0, stream>>>((const float4*)W2, (uint2*)w2b, VOC * MID / 4);

  // 4+5) chunked GEMM1 -> GEMM2 over M
  for (int r0 = 0; r0 < NN; r0 += max_rows) {
    int mrows = (NN - r0 < max_rows) ? (NN - r0) : max_rows;
    dim3 g1(MID / 128, (mrows + 127) / 128);
    k_gemm_bt<true><<<g1, 256, 0, stream>>>(hb + (size_t)r0 * HID, w1b, b1,
                                            (void*)h1b, mrows, MID, HID);
    dim3 g2(VOC / 128, (mrows + 127) / 128);
    k_gemm_bt<false><<<g2, 256, 0, stream>>>(h1b, w2b, b2,
                                             (void*)(out + (size_t)r0 * VOC), mrows, VOC, MID);
  }
}

// Round 5
// 1840.096 us; speedup vs baseline: 3.7158x; 1.3653x over previous
//
#include <hip/hip_runtime.h>
#include <hip/hip_bf16.h>
#include <stdint.h>

// Problem constants
#define NN 20000      // nodes
#define NE 640000     // edges
#define HID 512
#define MID 4352
#define VOC 8192

typedef __attribute__((ext_vector_type(4))) float f32x4;
typedef __attribute__((ext_vector_type(8))) short bf16x8;

__device__ __forceinline__ unsigned short f2bf(float f) {
  unsigned int u = __float_as_uint(f);
  u += 0x7fffu + ((u >> 16) & 1u);   // round-to-nearest-even
  return (unsigned short)(u >> 16);
}

// ---------------- detect edge_index storage width ----------------
__global__ void k_detect64(const int* __restrict__ ei32, int* __restrict__ flag) {
  __shared__ int any_nz;
  if (threadIdx.x == 0) any_nz = 0;
  __syncthreads();
  int v = ei32[2 * threadIdx.x + 1];
  if (v != 0) atomicOr(&any_nz, 1);
  __syncthreads();
  if (threadIdx.x == 0) *flag = (any_nz == 0) ? 1 : 0;  // 1 => int64 layout
}

__global__ void k_zero_i32(int* __restrict__ p, int n) {
  int i = blockIdx.x * blockDim.x + threadIdx.x;
  if (i < n) p[i] = 0;
}

__global__ void k_count(const int* __restrict__ ei, const int* __restrict__ flag,
                        int* __restrict__ deg) {
  int e = blockIdx.x * blockDim.x + threadIdx.x;
  if (e >= NE) return;
  int is64 = *flag;
  int d = is64 ? ei[2 * (NE + e)] : ei[NE + e];
  if ((unsigned)d >= NN) return;
  atomicAdd(&deg[d], 1);
}

__global__ __launch_bounds__(1024)
void k_scan(const int* __restrict__ deg, int* __restrict__ offs, int* __restrict__ cursor) {
  __shared__ int part[1024];
  const int t = threadIdx.x;
  const int CH = (NN + 1023) / 1024;  // 20
  const int base = t * CH;
  int s = 0;
  for (int i = 0; i < CH; ++i) { int idx = base + i; if (idx < NN) s += deg[idx]; }
  part[t] = s;
  __syncthreads();
  for (int off = 1; off < 1024; off <<= 1) {
    int v = (t >= off) ? part[t - off] : 0;
    __syncthreads();
    part[t] += v;
    __syncthreads();
  }
  int run = (t == 0) ? 0 : part[t - 1];  // exclusive prefix
  for (int i = 0; i < CH; ++i) {
    int idx = base + i;
    if (idx < NN) { offs[idx] = run; cursor[idx] = run; run += deg[idx]; }
  }
}

__global__ void k_fill(const int* __restrict__ ei, const int* __restrict__ flag,
                       int* __restrict__ cursor, int* __restrict__ csr) {
  int e = blockIdx.x * blockDim.x + threadIdx.x;
  if (e >= NE) return;
  int is64 = *flag;
  int s, d;
  if (is64) { s = ei[2 * e]; d = ei[2 * (NE + e)]; }
  else      { s = ei[e];     d = ei[NE + e]; }
  if ((unsigned)s >= NN || (unsigned)d >= NN) return;
  int pos = atomicAdd(&cursor[d], 1);
  csr[pos] = s;
}

// ---------------- fused gather + (1+eps)*x + bf16 convert ----------------
__global__ __launch_bounds__(256)
void k_gather_bf16(const float4* __restrict__ x4, const int* __restrict__ offs,
                   const int* __restrict__ deg, const int* __restrict__ csr,
                   uint4* __restrict__ hb4) {
  const int wid = blockIdx.x * (blockDim.x >> 6) + (threadIdx.x >> 6);
  if (wid >= NN) return;
  const int lane = threadIdx.x & 63;
  const long long rb0 = (long long)wid * 128 + lane * 2;
  float4 a0 = x4[rb0];
  float4 a1 = x4[rb0 + 1];
  const int beg = offs[wid];
  const int dc  = deg[wid];
  for (int j = 0; j < dc; ++j) {
    int s = csr[beg + j];
    long long rb = (long long)s * 128 + lane * 2;
    float4 v0 = x4[rb];
    float4 v1 = x4[rb + 1];
    a0.x += v0.x; a0.y += v0.y; a0.z += v0.z; a0.w += v0.w;
    a1.x += v1.x; a1.y += v1.y; a1.z += v1.z; a1.w += v1.w;
  }
  uint4 o;
  o.x = (unsigned)f2bf(a0.x) | ((unsigned)f2bf(a0.y) << 16);
  o.y = (unsigned)f2bf(a0.z) | ((unsigned)f2bf(a0.w) << 16);
  o.z = (unsigned)f2bf(a1.x) | ((unsigned)f2bf(a1.y) << 16);
  o.w = (unsigned)f2bf(a1.z) | ((unsigned)f2bf(a1.w) << 16);
  hb4[(long long)wid * 64 + lane] = o;
}

__global__ void k_f32_to_bf16(const float4* __restrict__ src, uint2* __restrict__ dst, int n4) {
  int i = blockIdx.x * blockDim.x + threadIdx.x;
  int stride = gridDim.x * blockDim.x;
  for (; i < n4; i += stride) {
    float4 v = src[i];
    uint2 o;
    o.x = (unsigned)f2bf(v.x) | ((unsigned)f2bf(v.y) << 16);
    o.y = (unsigned)f2bf(v.z) | ((unsigned)f2bf(v.w) << 16);
    dst[i] = o;
  }
}

// =================== 256x256 8-phase bf16 GEMM ===================
// C[M,N] = A[M,K] * B[N,K]^T + bias.  BK=64, 512 thr = 8 waves (2Mx4N),
// per-wave 128x64 output. LDS 128KB = 2 K-tile buffers (even->buf0, odd->buf1).
// 8 phases / 2 K-tiles per iteration; counted vmcnt(2) at P4/P8 only (T3+T4).
// seg-swizzle phys_seg = seg ^ (row&7), both-sides (pre-swizzled global src
// for global_load_lds linear dest + swizzled ds_read) -> 0 bank conflicts.

#define SBAR  __builtin_amdgcn_s_barrier()
#define LGKM0 asm volatile("s_waitcnt lgkmcnt(0)" ::: "memory")
#define SCHB  __builtin_amdgcn_sched_barrier(0)
#define VMC(n) asm volatile("s_waitcnt vmcnt(" #n ")" ::: "memory")
#define PRIO1 __builtin_amdgcn_s_setprio(1)
#define PRIO0 __builtin_amdgcn_s_setprio(0)

#define READ_A(qm, bufc) \
  _Pragma("unroll") for (int m_ = 0; m_ < 4; ++m_) { \
    const char* p_ = (bufc) + aOff + (qm) * 8192 + m_ * 2048; \
    aF[m_][0] = *(const bf16x8*)(p_ + sg0); \
    aF[m_][1] = *(const bf16x8*)(p_ + sg1); \
  }

#define READ_B(qn, bufc, DST) \
  _Pragma("unroll") for (int n_ = 0; n_ < 2; ++n_) { \
    const char* p_ = (bufc) + 32768 + bOff + (qn) * 4096 + n_ * 2048; \
    DST[n_][0] = *(const bf16x8*)(p_ + sg0); \
    DST[n_][1] = *(const bf16x8*)(p_ + sg1); \
  }

#define MFMA_Q(qm, qn, BQ) \
  _Pragma("unroll") for (int m_ = 0; m_ < 4; ++m_) \
    _Pragma("unroll") for (int n_ = 0; n_ < 2; ++n_) { \
      acc[(qm)*4+m_][(qn)*2+n_] = __builtin_amdgcn_mfma_f32_16x16x32_bf16( \
          aF[m_][0], BQ[n_][0], acc[(qm)*4+m_][(qn)*2+n_], 0, 0, 0); \
      acc[(qm)*4+m_][(qn)*2+n_] = __builtin_amdgcn_mfma_f32_16x16x32_bf16( \
          aF[m_][1], BQ[n_][1], acc[(qm)*4+m_][(qn)*2+n_], 0, 0, 0); \
    }

#define STAGE_A(bufc, kt, ha) \
  _Pragma("unroll") for (int j_ = 0; j_ < 2; ++j_) { \
    int rl_ = (ha) * 128 + (w * 2 + j_) * 8 + stSub; \
    int gr_ = aRow0 + rl_; if (gr_ > Mm1) gr_ = Mm1; \
    __builtin_amdgcn_global_load_lds( \
      (const __attribute__((address_space(1))) void*)(A + (long long)gr_ * K + (kt) * 64 + stSeg8), \
      (__attribute__((address_space(3))) void*)((bufc) + (ha) * 16384 + (w * 2 + j_) * 1024), \
      16, 0, 0); \
  }

#define STAGE_B(bufc, kt, ha) \
  _Pragma("unroll") for (int j_ = 0; j_ < 2; ++j_) { \
    int rl_ = (ha) * 128 + (w * 2 + j_) * 8 + stSub; \
    int gr_ = bRow0 + rl_; \
    __builtin_amdgcn_global_load_lds( \
      (const __attribute__((address_space(1))) void*)(B + (long long)gr_ * K + (kt) * 64 + stSeg8), \
      (__attribute__((address_space(3))) void*)((bufc) + 32768 + (ha) * 16384 + (w * 2 + j_) * 1024), \
      16, 0, 0); \
  }

template<bool OUT_BF16>
__global__ __launch_bounds__(512, 2)
void k_gemm256(const unsigned short* __restrict__ A,   // [M,K] bf16
               const unsigned short* __restrict__ B,   // [N,K] bf16
               const float* __restrict__ bias,         // [N]
               void* __restrict__ C,                   // [M,N] f32 or bf16
               int M, int N, int K)
{
  __shared__ __align__(16) char lds[131072];   // 2 x (A 32KB + B 32KB)

  const int tid  = threadIdx.x;
  const int lane = tid & 63;
  const int w    = tid >> 6;       // 0..7
  const int wr   = w >> 2;         // 0..1  (M)
  const int wc   = w & 3;          // 0..3  (N)

  // grid mapping: bn-chunk per XCD if possible, else m204 bijective swizzle
  const int nwg  = gridDim.x * gridDim.y;
  const int orig = blockIdx.y * gridDim.x + blockIdx.x;
  int bn, bm;
  if ((gridDim.x & 7) == 0 && (nwg & 7) == 0) {
    const int xcd = orig & 7;
    const int j   = orig >> 3;
    const int chunk = gridDim.x >> 3;
    bn = xcd * chunk + (j % chunk);
    bm = j / chunk;
  } else {
    const int q = nwg >> 3, r = nwg & 7;
    const int xcd = orig & 7, land = orig >> 3;
    const int nid = (xcd < r ? xcd * (q + 1) : r * (q + 1) + (xcd - r) * q) + land;
    bn = nid % gridDim.x;
    bm = nid / gridDim.x;
  }

  // per-lane constants
  const int lm = lane & 15;
  const int lk = lane >> 4;                       // 0..3
  const int l7 = lane & 7;
  const int sg0 = ((lk    ) ^ l7) * 16;           // swizzled seg byte off, ks=0
  const int sg1 = ((lk + 4) ^ l7) * 16;           // ks=1
  const int aOff = (wr * 128 + lm) * 128;         // A read base (bytes)
  const int bOff = (wc * 64  + lm) * 128;         // B read base (bytes)
  const int stSub  = lane >> 3;                   // 0..7
  const int stSeg8 = ((lane & 7) ^ stSub) * 8;    // pre-swizzled source seg (elems)
  const int aRow0 = bm * 256;
  const int bRow0 = bn * 256;
  const int Mm1 = M - 1;

  char* lb0 = (char*)lds;            // even K-tiles
  char* lb1 = (char*)lds + 65536;    // odd K-tiles

  f32x4 acc[8][4] = {};
  bf16x8 aF[4][2], bF0[2][2], bF1[2][2];

  const int nkt = K >> 6;            // 64-wide K tiles (even count required)
  const int nit = nkt >> 1;

  // prologue: tile0 full + tile1.A0
  STAGE_A(lb0, 0, 0); STAGE_A(lb0, 0, 1); STAGE_B(lb0, 0, 0); STAGE_B(lb0, 0, 1);
  STAGE_A(lb1, 1, 0);
  VMC(2);
  SBAR;

  for (int i = 0; i < nit; ++i) {
    const int ktO = 2 * i + 1;
    int ktE2 = 2 * i + 2; if (ktE2 >= nkt) ktE2 = nkt - 1;  // clamped junk on last iter
    int ktO2 = 2 * i + 3; if (ktO2 >= nkt) ktO2 = nkt - 1;
    // P1: tile E quad(0,0)
    READ_A(0, lb0); READ_B(0, lb0, bF0);
    STAGE_A(lb1, ktO, 1);
    SBAR; LGKM0; SCHB; PRIO1; MFMA_Q(0, 0, bF0); PRIO0; SBAR;
    // P2: quad(0,1)
    READ_B(1, lb0, bF1);
    STAGE_B(lb1, ktO, 0);
    SBAR; LGKM0; SCHB; PRIO1; MFMA_Q(0, 1, bF1); PRIO0; SBAR;
    // P3: quad(1,1)
    READ_A(1, lb0);
    STAGE_B(lb1, ktO, 1);
    SBAR; LGKM0; SCHB; PRIO1; MFMA_Q(1, 1, bF1); PRIO0; SBAR;
    // P4: quad(1,0)  (no new reads)
    STAGE_A(lb0, ktE2, 0);
    SBAR; PRIO1; MFMA_Q(1, 0, bF0); PRIO0; VMC(2); SBAR;
    // P5: tile O quad(0,0)
    READ_A(0, lb1); READ_B(0, lb1, bF0);
    STAGE_A(lb0, ktE2, 1);
    SBAR; LGKM0; SCHB; PRIO1; MFMA_Q(0, 0, bF0); PRIO0; SBAR;
    // P6: quad(0,1)
    READ_B(1, lb1, bF1);
    STAGE_B(lb0, ktE2, 0);
    SBAR; LGKM0; SCHB; PRIO1; MFMA_Q(0, 1, bF1); PRIO0; SBAR;
    // P7: quad(1,1)
    READ_A(1, lb1);
    STAGE_B(lb0, ktE2, 1);
    SBAR; LGKM0; SCHB; PRIO1; MFMA_Q(1, 1, bF1); PRIO0; SBAR;
    // P8: quad(1,0)
    STAGE_A(lb1, ktO2, 0);
    SBAR; PRIO1; MFMA_Q(1, 0, bF0); PRIO0; VMC(2); SBAR;
  }

  // epilogue: C[row, col] = acc + bias
#pragma unroll
  for (int in = 0; in < 4; ++in) {
    const int col = bn * 256 + wc * 64 + in * 16 + lm;
    const float bv = bias[col];
#pragma unroll
    for (int im = 0; im < 8; ++im) {
      const int row0 = bm * 256 + wr * 128 + im * 16 + lk * 4;
#pragma unroll
      for (int jj = 0; jj < 4; ++jj) {
        const int row = row0 + jj;
        if (row < M) {
          const float v = acc[im][in][jj] + bv;
          if (OUT_BF16)
            __builtin_nontemporal_store(f2bf(v), &((unsigned short*)C)[(long long)row * N + col]);
          else
            __builtin_nontemporal_store(v, &((float*)C)[(long long)row * N + col]);
        }
      }
    }
  }
}

extern "C" void kernel_launch(void* const* d_in, const int* in_sizes, int n_in,
                              void* d_out, int out_size, void* d_ws, size_t ws_size,
                              hipStream_t stream) {
  const float* x  = (const float*)d_in[0];
  const int*   ei = (const int*)d_in[1];      // int32 or int64 — detected on device
  const float* W1 = (const float*)d_in[2];
  const float* b1 = (const float*)d_in[3];
  const float* W2 = (const float*)d_in[4];
  const float* b2 = (const float*)d_in[5];
  float* out = (float*)d_out;
  char* ws = (char*)d_ws;

  // workspace layout (bytes, 16B-aligned)
  int* flag            = (int*)(ws + 0);                 // 256
  int* deg             = (int*)(ws + 256);               // 80,000
  int* offs            = (int*)(ws + 80256);             // 80,000
  int* cursor          = (int*)(ws + 160256);            // 80,000
  int* csr             = (int*)(ws + 240256);            // 2,560,000
  unsigned short* hb   = (unsigned short*)(ws + 2800256);   // 20,480,000
  unsigned short* w1b  = (unsigned short*)(ws + 23280256);  //  4,456,448
  unsigned short* w2b  = (unsigned short*)(ws + 27736704);  // 71,303,168
  const size_t h1_off  = 99039872;
  if (ws_size < h1_off + (size_t)256 * MID * 2) return;
  unsigned short* h1b  = (unsigned short*)(ws + h1_off);

  long long rem = (long long)ws_size - (long long)h1_off;
  int max_rows = (int)(rem / ((long long)MID * 2));
  max_rows = (max_rows / 256) * 256;
  if (max_rows > 20224) max_rows = 20224;

  // 0) detect edge_index width
  k_detect64<<<1, 256, 0, stream>>>(ei, flag);

  // 1) CSR build
  k_zero_i32<<<(NN + 255) / 256, 256, 0, stream>>>(deg, NN);
  k_count<<<(NE + 255) / 256, 256, 0, stream>>>(ei, flag, deg);
  k_scan<<<1, 1024, 0, stream>>>(deg, offs, cursor);
  k_fill<<<(NE + 255) / 256, 256, 0, stream>>>(ei, flag, cursor, csr);

  // 2) fused gather + bf16 convert: hb = bf16(x + sum_{j->i} x_j)
  k_gather_bf16<<<(NN + 3) / 4, 256, 0, stream>>>((const float4*)x, offs, deg, csr,
                                                  (uint4*)hb);

  // 3) weight conversions to bf16
  k_f32_to_bf16<<<1024, 256, 0, stream>>>((const float4*)W1, (uint2*)w1b, MID * HID / 4);
  k_f32_to_bf16<<<2048, 256, 0, stream>>>((const float4*)W2, (uint2*)w2b, VOC * MID / 4);

  // 4+5) chunked GEMM1 -> GEMM2 over M (usually a single chunk)
  for (int r0 = 0; r0 < NN; r0 += max_rows) {
    int mrows = (NN - r0 < max_rows) ? (NN - r0) : max_rows;
    dim3 g1(MID / 256, (mrows + 255) / 256);
    k_gemm256<true><<<g1, 512, 0, stream>>>(hb + (size_t)r0 * HID, w1b, b1,
                                            (void*)h1b, mrows, MID, HID);
    dim3 g2(VOC / 256, (mrows + 255) / 256);
    k_gemm256<false><<<g2, 512, 0, stream>>>(h1b, w2b, b2,
                                             (void*)(out + (size_t)r0 * VOC), mrows, VOC, MID);
  }
}